// Round 4
// baseline (50.976 us; speedup 1.0000x reference)
//
#include <hip/hip_runtime.h>

// IAF spiking layer: data (B*T, F) fp32, B=32, T=1024, F=1024.
// One thread per (b,f) chain; t strictly sequential; 512 waves (2/CU).
// R3 vs R1 (44.6 us): shrink vmcnt ops/chunk 20 -> 16 by transposing the
// output through LDS (8x global_store_dwordx4 per 32 t-steps instead of 32
// scalar stores), DEPTH 16 -> 32, issue-first prefetch depth 3 -> 5
// (40 KB/wave = 80 KB/CU in flight ~ 8.7x BW*latency), and a shorter
// dependent chain: a = floor(max(s,0)) == (s>0 ? floor(s) : 0) bit-exact.
//
// vmcnt accounting (8 load_lds + 8 dwordx4-store per chunk, order pinned by
// sched_barrier(0) + asm memory clobbers; issue-first: wait, L(c+4), C(c)):
//   head 24/32/40/48, steady 56, tail 56/48/40/32.

constexpr int T = 1024;
constexpr int F = 1024;
constexpr int DEPTH = 32;                  // t-steps per chunk
constexpr int NC = T / DEPTH;              // 32 chunks
constexpr int CH = DEPTH * 64;             // 2048 floats = 8 KB per buffer
constexpr int RING = 6;                    // ring buffers (need >= 6 for P=5)

#define WAITVM(N) asm volatile("s_waitcnt vmcnt(" #N ")" ::: "memory")
#define LGKM0()   asm volatile("s_waitcnt lgkmcnt(0)" ::: "memory")
#define SFENCE()  __builtin_amdgcn_sched_barrier(0)

__global__ __launch_bounds__(64) void iaf_kernel(const float* __restrict__ x,
                                                 float* __restrict__ out) {
    __shared__ float ring[RING * CH];      // 48 KB input ring
    __shared__ float outT[DEPTH * 64];     // 8 KB output transpose tile

    const int lane = threadIdx.x;          // 0..63
    const int b = blockIdx.x >> 4;         // 32 batch rows
    const int f0 = (blockIdx.x & 15) * 64; // feature block base

    const size_t base = ((size_t)b * T) * F + f0;
    const float* __restrict__ p = x + base;      // row t at p + t*F
    float* __restrict__ qo = out + base;

    // global_load_lds lane map (verified R1/R2, absmax 0): instr r covers
    // global row k*32 + r*4 + (lane>>4), floats f0 + (lane&15)*4 .. +3;
    // LDS dest linear (base + lane*16B) == row-major [32][64] float tile.
    const int lrow = lane >> 4;            // 0..3
    const int lcol = (lane & 15) * 4;      // float col within 64-wide block

    float s = 0.0f, a = 0.0f;

    auto issue = [&](int k, int rb) {      // 8x 16B global_load_lds
        float* lb = &ring[rb * CH];
#pragma unroll
        for (int r = 0; r < 8; ++r) {
            const float* g = p + (size_t)(k * DEPTH + r * 4 + lrow) * F + lcol;
            __builtin_amdgcn_global_load_lds(
                (const __attribute__((address_space(1))) void*)g,
                (__attribute__((address_space(3))) void*)(lb + r * 256),
                16, 0, 0);
        }
        SFENCE();
    };

    auto compute = [&](int k, int rb) {
        const float* lb = &ring[rb * CH];
        // 32 recurrence steps; write spikes to transpose tile (col = lane).
        // ds_read/ds_write banks: all lanes same row -> bank = lane%32,
        // 2 lanes/bank (free).
#pragma unroll
        for (int i = 0; i < DEPTH; ++i) {
            const float xv = lb[i * 64 + lane];
            // exact reference op order (bit-exact floor/relu feedback):
            s = (xv + s) - a;
            s = fmaxf(s + 1.0f, 0.0f) - 1.0f;    // relu(s - (-1)) + (-1)
            a = floorf(fmaxf(s, 0.0f));          // == (s>0)?floor(s):0
            outT[i * 64 + lane] = a;
        }
        LGKM0();                               // wave-private: all 64 lanes'
        SFENCE();                              // writes issued before reads
        // transpose out: instr j covers t-rows 4j..4j+3; lane -> row 4j+lrow,
        // cols lcol..lcol+3. 8x ds_read_b128 + 8x global_store_dwordx4 (1KB).
#pragma unroll
        for (int j = 0; j < 8; ++j) {
            const int row = j * 4 + lrow;
            const float4 v = *(const float4*)&outT[row * 64 + lcol];
            *(float4*)(qo + (size_t)(k * DEPTH + row) * F + lcol) = v;
        }
        SFENCE();
    };

    // prologue: 4 chunks in flight (P=5 reached after first issue-first iter)
    issue(0, 0); issue(1, 1); issue(2, 2); issue(3, 3);

    // head peels (exact ops-after-L(c) counts)
    WAITVM(24); issue(4, 4); compute(0, 0);
    WAITVM(32); issue(5, 5); compute(1, 1);
    WAITVM(40); issue(6, 0); compute(2, 2);
    WAITVM(48); issue(7, 1); compute(3, 3);

    // steady state: ops after L(c) = S(c-4) + 3*(L+S) = 8 + 48 = 56
    int bc = 4, bl = 2;                    // c=4: compute buf 4%6, issue buf 8%6
    for (int c = 4; c <= 27; ++c) {
        WAITVM(56);
        issue(c + 4, bl);
        compute(c, bc);
        bc = (bc == RING - 1) ? 0 : bc + 1;
        bl = (bl == RING - 1) ? 0 : bl + 1;
    }

    // tail (exact counts)
    WAITVM(56); compute(28, 4);
    WAITVM(48); compute(29, 5);
    WAITVM(40); compute(30, 0);
    WAITVM(32); compute(31, 1);
}

extern "C" void kernel_launch(void* const* d_in, const int* in_sizes, int n_in,
                              void* d_out, int out_size, void* d_ws, size_t ws_size,
                              hipStream_t stream) {
    const float* x = (const float*)d_in[0];
    float* out = (float*)d_out;
    // 512 blocks x 64 threads = 32768 chains; LDS 56 KB -> 2 blocks/CU.
    iaf_kernel<<<dim3(512), dim3(64), 0, stream>>>(x, out);
}